// Round 1
// baseline (217.199 us; speedup 1.0000x reference)
//
#include <hip/hip_runtime.h>

#define N 768
#define E 24576

// ---------------------------------------------------------------------------
// Transpose mtr [i][j][8] -> mtrT [j][i][8] so the contraction reads rows.
// 16x16 (i,j) tiles of 8-float elements through LDS.
// ---------------------------------------------------------------------------
__global__ __launch_bounds__(256) void transpose_mtr(
    const float* __restrict__ mtr, float* __restrict__ mtrT) {
  __shared__ float lds[16][16 * 8 + 4];
  const int r = threadIdx.x >> 4;  // 0..15
  const int c = threadIdx.x & 15;  // 0..15
  const size_t i0 = (size_t)blockIdx.y * 16;
  const size_t j0 = (size_t)blockIdx.x * 16;

  const float4* src = (const float4*)(mtr + ((i0 + r) * N + (j0 + c)) * 8);
  float4 a = src[0], b = src[1];
  *(float4*)&lds[r][c * 8 + 0] = a;
  *(float4*)&lds[r][c * 8 + 4] = b;
  __syncthreads();
  float4* dst = (float4*)(mtrT + ((j0 + r) * N + (i0 + c)) * 8);
  dst[0] = *(float4*)&lds[c][r * 8 + 0];
  dst[1] = *(float4*)&lds[c][r * 8 + 4];
}

// ---------------------------------------------------------------------------
// Edge MLP: 20 -> 32 -> 32 -> 32 -> 64, ReLU between hidden layers.
// Also: winner[src*N+dst] = max edge id (last-write-wins .set semantics),
// and histogram of destination degrees for the CSR build.
// ---------------------------------------------------------------------------
__global__ __launch_bounds__(256) void edge_mlp(
    const float* __restrict__ feat, const int* __restrict__ ei,
    const float* __restrict__ ea,
    const float* __restrict__ w0, const float* __restrict__ b0,
    const float* __restrict__ w1, const float* __restrict__ b1,
    const float* __restrict__ w2, const float* __restrict__ b2,
    const float* __restrict__ w3, const float* __restrict__ b3,
    float* __restrict__ evals, int* __restrict__ winner,
    int* __restrict__ deg) {
  const int e = blockIdx.x * 256 + threadIdx.x;
  if (e >= E) return;
  const int s = ei[e];
  const int d = ei[E + e];

  float x[20];
  {
    float4 t = *(const float4*)(ea + (size_t)e * 4);
    x[0] = t.x; x[1] = t.y; x[2] = t.z; x[3] = t.w;
    float4 f0 = *(const float4*)(feat + (size_t)s * 8);
    float4 f1 = *(const float4*)(feat + (size_t)s * 8 + 4);
    x[4] = f0.x; x[5] = f0.y; x[6] = f0.z; x[7] = f0.w;
    x[8] = f1.x; x[9] = f1.y; x[10] = f1.z; x[11] = f1.w;
    float4 g0 = *(const float4*)(feat + (size_t)d * 8);
    float4 g1 = *(const float4*)(feat + (size_t)d * 8 + 4);
    x[12] = g0.x; x[13] = g0.y; x[14] = g0.z; x[15] = g0.w;
    x[16] = g1.x; x[17] = g1.y; x[18] = g1.z; x[19] = g1.w;
  }

  float h[32];
#pragma unroll
  for (int o = 0; o < 32; ++o) {
    float acc = b0[o];
#pragma unroll
    for (int c = 0; c < 20; ++c) acc = fmaf(w0[o * 20 + c], x[c], acc);
    h[o] = fmaxf(acc, 0.f);
  }

#pragma unroll 1
  for (int l = 0; l < 2; ++l) {
    const float* W = l ? w2 : w1;
    const float* B = l ? b2 : b1;
    float g[32];
#pragma unroll
    for (int o = 0; o < 32; ++o) {
      float acc = B[o];
#pragma unroll
      for (int c = 0; c < 32; ++c) acc = fmaf(W[o * 32 + c], h[c], acc);
      g[o] = fmaxf(acc, 0.f);
    }
#pragma unroll
    for (int o = 0; o < 32; ++o) h[o] = g[o];
  }

  float* erow = evals + (size_t)e * 64;
#pragma unroll
  for (int o4 = 0; o4 < 16; ++o4) {
    float r[4];
#pragma unroll
    for (int q = 0; q < 4; ++q) {
      const int o = o4 * 4 + q;
      float acc = b3[o];
#pragma unroll
      for (int c = 0; c < 32; ++c) acc = fmaf(w3[o * 32 + c], h[c], acc);
      r[q] = acc;
    }
    *(float4*)(erow + o4 * 4) = make_float4(r[0], r[1], r[2], r[3]);
  }

  atomicMax(&winner[(size_t)s * N + d], e);
  atomicAdd(&deg[d], 1);
}

// ---------------------------------------------------------------------------
// Inclusive scan of deg[0..N) -> offs[1..N], offs[0] = 0. One block.
// ---------------------------------------------------------------------------
__global__ void scan_offs(const int* __restrict__ deg, int* __restrict__ offs) {
  __shared__ int s[N];
  const int t = threadIdx.x;
  s[t] = deg[t];
  __syncthreads();
#pragma unroll 1
  for (int d = 1; d < N; d <<= 1) {
    int v = (t >= d) ? s[t - d] : 0;
    __syncthreads();
    s[t] += v;
    __syncthreads();
  }
  offs[t + 1] = s[t];
  if (t == 0) offs[0] = 0;
}

// ---------------------------------------------------------------------------
// Scatter edge ids into destination buckets (CSR by dst).
// ---------------------------------------------------------------------------
__global__ __launch_bounds__(256) void scatter_edges(
    const int* __restrict__ ei, const int* __restrict__ offs,
    int* __restrict__ curs, int* __restrict__ elist) {
  const int e = blockIdx.x * 256 + threadIdx.x;
  if (e >= E) return;
  const int d = ei[E + e];
  const int pos = offs[d] + atomicAdd(&curs[d], 1);
  elist[pos] = e;
}

// ---------------------------------------------------------------------------
// Walk contraction: WT[k][i][t] = (1/8) * sum over edges (j->k), c of
//   mtrT[j][i][c] * evals[e][c*8+t]
// One block per destination k; 256 threads, 3 rows each.
// Skips non-winner duplicate edges (set semantics).
// ---------------------------------------------------------------------------
__global__ __launch_bounds__(256) void contract(
    const float* __restrict__ mtrT, const float* __restrict__ evals,
    const int* __restrict__ ei, const int* __restrict__ elist,
    const int* __restrict__ offs, const int* __restrict__ winner,
    float* __restrict__ WT) {
  const int k = blockIdx.x;
  const int tid = threadIdx.x;

  float acc[3][8];
#pragma unroll
  for (int r = 0; r < 3; ++r)
#pragma unroll
    for (int t = 0; t < 8; ++t) acc[r][t] = 0.f;

  const int beg = offs[k];
  const int end = offs[k + 1];
  for (int xx = beg; xx < end; ++xx) {
    const int e = elist[xx];
    const int j = ei[e];
    if (winner[(size_t)j * N + k] != e) continue;  // uniform branch

    const float* M = evals + (size_t)e * 64;
    float m[64];
#pragma unroll
    for (int z = 0; z < 16; ++z) {
      float4 t = ((const float4*)M)[z];
      m[z * 4 + 0] = t.x; m[z * 4 + 1] = t.y;
      m[z * 4 + 2] = t.z; m[z * 4 + 3] = t.w;
    }

#pragma unroll
    for (int r = 0; r < 3; ++r) {
      const int i = tid + r * 256;
      const float* row = mtrT + ((size_t)j * N + i) * 8;
      float4 a = ((const float4*)row)[0];
      float4 b = ((const float4*)row)[1];
      float v[8] = {a.x, a.y, a.z, a.w, b.x, b.y, b.z, b.w};
#pragma unroll
      for (int c = 0; c < 8; ++c)
#pragma unroll
        for (int t = 0; t < 8; ++t)
          acc[r][t] = fmaf(v[c], m[c * 8 + t], acc[r][t]);
    }
  }

#pragma unroll
  for (int r = 0; r < 3; ++r) {
    const int i = tid + r * 256;
    float* dst = WT + ((size_t)k * N + i) * 8;
    *(float4*)(dst + 0) = make_float4(acc[r][0] * 0.125f, acc[r][1] * 0.125f,
                                      acc[r][2] * 0.125f, acc[r][3] * 0.125f);
    *(float4*)(dst + 4) = make_float4(acc[r][4] * 0.125f, acc[r][5] * 0.125f,
                                      acc[r][6] * 0.125f, acc[r][7] * 0.125f);
  }
}

// ---------------------------------------------------------------------------
// Output MLP: x[33] = [mtr1[i,k,:], mtr1[k,i,:], feat[k], feat[i], (i==k)]
// 33 -> 32 -> 32 -> 32 -> 8, residual add with mtr.
// One thread per (i,k); 16x16 tile per block.
// ---------------------------------------------------------------------------
__global__ __launch_bounds__(256) void out_mlp(
    const float* __restrict__ mtr, const float* __restrict__ WT,
    const float* __restrict__ feat,
    const float* __restrict__ w0, const float* __restrict__ b0,
    const float* __restrict__ w1, const float* __restrict__ b1,
    const float* __restrict__ w2, const float* __restrict__ b2,
    const float* __restrict__ w3, const float* __restrict__ b3,
    float* __restrict__ out) {
  const int i = blockIdx.y * 16 + (threadIdx.x & 15);
  const int k = blockIdx.x * 16 + (threadIdx.x >> 4);

  float x[33];
  {
    const float* p1 = WT + ((size_t)k * N + i) * 8;  // mtr1[i,k,:]
    const float* p2 = WT + ((size_t)i * N + k) * 8;  // mtr1[k,i,:]
    float4 a0 = ((const float4*)p1)[0], a1 = ((const float4*)p1)[1];
    float4 b0v = ((const float4*)p2)[0], b1v = ((const float4*)p2)[1];
    x[0] = a0.x; x[1] = a0.y; x[2] = a0.z; x[3] = a0.w;
    x[4] = a1.x; x[5] = a1.y; x[6] = a1.z; x[7] = a1.w;
    x[8] = b0v.x; x[9] = b0v.y; x[10] = b0v.z; x[11] = b0v.w;
    x[12] = b1v.x; x[13] = b1v.y; x[14] = b1v.z; x[15] = b1v.w;
    float4 fk0 = ((const float4*)(feat + (size_t)k * 8))[0];
    float4 fk1 = ((const float4*)(feat + (size_t)k * 8))[1];
    float4 fi0 = ((const float4*)(feat + (size_t)i * 8))[0];
    float4 fi1 = ((const float4*)(feat + (size_t)i * 8))[1];
    x[16] = fk0.x; x[17] = fk0.y; x[18] = fk0.z; x[19] = fk0.w;
    x[20] = fk1.x; x[21] = fk1.y; x[22] = fk1.z; x[23] = fk1.w;
    x[24] = fi0.x; x[25] = fi0.y; x[26] = fi0.z; x[27] = fi0.w;
    x[28] = fi1.x; x[29] = fi1.y; x[30] = fi1.z; x[31] = fi1.w;
    x[32] = (i == k) ? 1.f : 0.f;
  }

  float h[32];
#pragma unroll
  for (int o = 0; o < 32; ++o) {
    float acc = b0[o];
#pragma unroll
    for (int c = 0; c < 33; ++c) acc = fmaf(w0[o * 33 + c], x[c], acc);
    h[o] = fmaxf(acc, 0.f);
  }

#pragma unroll 1
  for (int l = 0; l < 2; ++l) {
    const float* W = l ? w2 : w1;
    const float* B = l ? b2 : b1;
    float g[32];
#pragma unroll
    for (int o = 0; o < 32; ++o) {
      float acc = B[o];
#pragma unroll
      for (int c = 0; c < 32; ++c) acc = fmaf(W[o * 32 + c], h[c], acc);
      g[o] = fmaxf(acc, 0.f);
    }
#pragma unroll
    for (int o = 0; o < 32; ++o) h[o] = g[o];
  }

  const size_t idx = ((size_t)i * N + k) * 8;
  float r[8];
#pragma unroll
  for (int t = 0; t < 8; ++t) {
    float acc = b3[t];
#pragma unroll
    for (int c = 0; c < 32; ++c) acc = fmaf(w3[t * 32 + c], h[c], acc);
    r[t] = acc;
  }
  *(float4*)(out + idx + 0) = make_float4(mtr[idx + 0] + r[0], mtr[idx + 1] + r[1],
                                          mtr[idx + 2] + r[2], mtr[idx + 3] + r[3]);
  *(float4*)(out + idx + 4) = make_float4(mtr[idx + 4] + r[4], mtr[idx + 5] + r[5],
                                          mtr[idx + 6] + r[6], mtr[idx + 7] + r[7]);
}

// ---------------------------------------------------------------------------
extern "C" void kernel_launch(void* const* d_in, const int* in_sizes, int n_in,
                              void* d_out, int out_size, void* d_ws,
                              size_t ws_size, hipStream_t stream) {
  const float* mtr  = (const float*)d_in[0];
  const float* feat = (const float*)d_in[1];
  const int*   ei   = (const int*)d_in[2];
  const float* ea   = (const float*)d_in[3];
  const float* ew0 = (const float*)d_in[4];
  const float* eb0 = (const float*)d_in[5];
  const float* ew1 = (const float*)d_in[6];
  const float* eb1 = (const float*)d_in[7];
  const float* ew2 = (const float*)d_in[8];
  const float* eb2 = (const float*)d_in[9];
  const float* ew3 = (const float*)d_in[10];
  const float* eb3 = (const float*)d_in[11];
  const float* ow0 = (const float*)d_in[12];
  const float* ob0 = (const float*)d_in[13];
  const float* ow1 = (const float*)d_in[14];
  const float* ob1 = (const float*)d_in[15];
  const float* ow2 = (const float*)d_in[16];
  const float* ob2 = (const float*)d_in[17];
  const float* ow3 = (const float*)d_in[18];
  const float* ob3 = (const float*)d_in[19];
  float* out = (float*)d_out;

  char* ws = (char*)d_ws;
  float* evals = (float*)ws; ws += (size_t)E * 64 * 4;       // 6.29 MB
  float* mtrT  = (float*)ws; ws += (size_t)N * N * 8 * 4;    // 18.87 MB
  float* WT    = (float*)ws; ws += (size_t)N * N * 8 * 4;    // 18.87 MB
  int* winner  = (int*)ws;   ws += (size_t)N * N * 4;        // 2.36 MB
  int* deg     = (int*)ws;   ws += 1024 * 4;
  int* offs    = (int*)ws;   ws += 1024 * 4;
  int* curs    = (int*)ws;   ws += 1024 * 4;
  int* elist   = (int*)ws;   ws += (size_t)E * 4;

  hipMemsetAsync(winner, 0xFF, (size_t)N * N * 4, stream);  // -1
  hipMemsetAsync(deg, 0, 1024 * 4, stream);
  hipMemsetAsync(curs, 0, 1024 * 4, stream);

  transpose_mtr<<<dim3(48, 48), 256, 0, stream>>>(mtr, mtrT);
  edge_mlp<<<E / 256, 256, 0, stream>>>(feat, ei, ea, ew0, eb0, ew1, eb1, ew2,
                                        eb2, ew3, eb3, evals, winner, deg);
  scan_offs<<<1, N, 0, stream>>>(deg, offs);
  scatter_edges<<<E / 256, 256, 0, stream>>>(ei, offs, curs, elist);
  contract<<<N, 256, 0, stream>>>(mtrT, evals, ei, elist, offs, winner, WT);
  out_mlp<<<dim3(48, 48), 256, 0, stream>>>(mtr, WT, feat, ow0, ob0, ow1, ob1,
                                            ow2, ob2, ow3, ob3, out);
}

// Round 2
// 196.007 us; speedup vs baseline: 1.1081x; 1.1081x over previous
//
#include <hip/hip_runtime.h>

#define N 768
#define E 24576

// ---------------------------------------------------------------------------
// Transpose mtr [i][j][8] -> mtrT [j][i][8] so the contraction reads rows.
// ---------------------------------------------------------------------------
__global__ __launch_bounds__(256) void transpose_mtr(
    const float* __restrict__ mtr, float* __restrict__ mtrT) {
  __shared__ float lds[16][16 * 8 + 4];
  const int r = threadIdx.x >> 4;  // 0..15
  const int c = threadIdx.x & 15;  // 0..15
  const size_t i0 = (size_t)blockIdx.y * 16;
  const size_t j0 = (size_t)blockIdx.x * 16;

  const float4* src = (const float4*)(mtr + ((i0 + r) * N + (j0 + c)) * 8);
  float4 a = src[0], b = src[1];
  *(float4*)&lds[r][c * 8 + 0] = a;
  *(float4*)&lds[r][c * 8 + 4] = b;
  __syncthreads();
  float4* dst = (float4*)(mtrT + ((j0 + r) * N + (i0 + c)) * 8);
  dst[0] = *(float4*)&lds[c][r * 8 + 0];
  dst[1] = *(float4*)&lds[c][r * 8 + 4];
}

// ---------------------------------------------------------------------------
// Edge MLP: 20 -> 32 -> 32 -> 32 -> 64 + winner marking + dst-degree histo.
// ---------------------------------------------------------------------------
__global__ __launch_bounds__(256) void edge_mlp(
    const float* __restrict__ feat, const int* __restrict__ ei,
    const float* __restrict__ ea,
    const float* __restrict__ w0, const float* __restrict__ b0,
    const float* __restrict__ w1, const float* __restrict__ b1,
    const float* __restrict__ w2, const float* __restrict__ b2,
    const float* __restrict__ w3, const float* __restrict__ b3,
    float* __restrict__ evals, int* __restrict__ winner,
    int* __restrict__ deg) {
  const int e = blockIdx.x * 256 + threadIdx.x;
  if (e >= E) return;
  const int s = ei[e];
  const int d = ei[E + e];

  float x[20];
  {
    float4 t = *(const float4*)(ea + (size_t)e * 4);
    x[0] = t.x; x[1] = t.y; x[2] = t.z; x[3] = t.w;
    float4 f0 = *(const float4*)(feat + (size_t)s * 8);
    float4 f1 = *(const float4*)(feat + (size_t)s * 8 + 4);
    x[4] = f0.x; x[5] = f0.y; x[6] = f0.z; x[7] = f0.w;
    x[8] = f1.x; x[9] = f1.y; x[10] = f1.z; x[11] = f1.w;
    float4 g0 = *(const float4*)(feat + (size_t)d * 8);
    float4 g1 = *(const float4*)(feat + (size_t)d * 8 + 4);
    x[12] = g0.x; x[13] = g0.y; x[14] = g0.z; x[15] = g0.w;
    x[16] = g1.x; x[17] = g1.y; x[18] = g1.z; x[19] = g1.w;
  }

  float h[32];
#pragma unroll
  for (int o = 0; o < 32; ++o) {
    float acc = b0[o];
#pragma unroll
    for (int c = 0; c < 20; ++c) acc = fmaf(w0[o * 20 + c], x[c], acc);
    h[o] = fmaxf(acc, 0.f);
  }

#pragma unroll 1
  for (int l = 0; l < 2; ++l) {
    const float* W = l ? w2 : w1;
    const float* B = l ? b2 : b1;
    float g[32];
#pragma unroll
    for (int o = 0; o < 32; ++o) {
      float acc = B[o];
#pragma unroll
      for (int c = 0; c < 32; ++c) acc = fmaf(W[o * 32 + c], h[c], acc);
      g[o] = fmaxf(acc, 0.f);
    }
#pragma unroll
    for (int o = 0; o < 32; ++o) h[o] = g[o];
  }

  float* erow = evals + (size_t)e * 64;
#pragma unroll
  for (int o4 = 0; o4 < 16; ++o4) {
    float r[4];
#pragma unroll
    for (int q = 0; q < 4; ++q) {
      const int o = o4 * 4 + q;
      float acc = b3[o];
#pragma unroll
      for (int c = 0; c < 32; ++c) acc = fmaf(w3[o * 32 + c], h[c], acc);
      r[q] = acc;
    }
    *(float4*)(erow + o4 * 4) = make_float4(r[0], r[1], r[2], r[3]);
  }

  atomicMax(&winner[(size_t)s * N + d], e);
  atomicAdd(&deg[d], 1);
}

// ---------------------------------------------------------------------------
// Inclusive scan of deg -> offs. One block of N threads.
// ---------------------------------------------------------------------------
__global__ void scan_offs(const int* __restrict__ deg, int* __restrict__ offs) {
  __shared__ int s[N];
  const int t = threadIdx.x;
  s[t] = deg[t];
  __syncthreads();
#pragma unroll 1
  for (int d = 1; d < N; d <<= 1) {
    int v = (t >= d) ? s[t - d] : 0;
    __syncthreads();
    s[t] += v;
    __syncthreads();
  }
  offs[t + 1] = s[t];
  if (t == 0) offs[0] = 0;
}

// ---------------------------------------------------------------------------
// Scatter only WINNING edges (set semantics) as packed {j, e} records.
// ---------------------------------------------------------------------------
__global__ __launch_bounds__(256) void scatter_edges(
    const int* __restrict__ ei, const int* __restrict__ winner,
    const int* __restrict__ offs, int* __restrict__ curs,
    int2* __restrict__ ejlist) {
  const int e = blockIdx.x * 256 + threadIdx.x;
  if (e >= E) return;
  const int s = ei[e];
  const int d = ei[E + e];
  if (winner[(size_t)s * N + d] != e) return;  // loser of duplicate (s,d)
  const int pos = offs[d] + atomicAdd(&curs[d], 1);
  ejlist[pos] = make_int2(s, e);
}

// ---------------------------------------------------------------------------
// Walk contraction v2.
// WT[k][i][t] = (1/8) * sum_{edges j->k, c} mtrT[j][i][c] * evals[e][c*8+t]
// One WAVE per k, i-tile of 64 per block; 12 i-tiles x 192 k-groups = 2304
// blocks. Block id decoded XCD-aware: blocks of the same i-tile land on the
// same XCD so the 1.57 MB mtrT slab stays L2-resident.
// ---------------------------------------------------------------------------
__global__ __launch_bounds__(256) void contract2(
    const float* __restrict__ mtrT, const float* __restrict__ evals,
    const int2* __restrict__ ejlist, const int* __restrict__ offs,
    const int* __restrict__ wcnt, float* __restrict__ WT) {
  const int b = blockIdx.x;
  const int x = b & 7;
  const int m = b >> 3;
  int t, kg;
  if (m < 192) { t = x; kg = m; }
  else { t = 8 + (x & 3); kg = (m - 192) * 2 + (x >> 2); }

  const int wave = threadIdx.x >> 6;
  const int lane = threadIdx.x & 63;
  const int k = kg * 4 + wave;
  const int i = t * 64 + lane;

  float acc[8];
#pragma unroll
  for (int q = 0; q < 8; ++q) acc[q] = 0.f;

  const int base = offs[k];
  const int cnt = wcnt[k];

#pragma unroll 2
  for (int xx = 0; xx < cnt; ++xx) {
    int2 je = ejlist[base + xx];
    const int j = __builtin_amdgcn_readfirstlane(je.x);
    const int e = __builtin_amdgcn_readfirstlane(je.y);

    const float* P = mtrT + ((size_t)j * N + i) * 8;
    float4 a = ((const float4*)P)[0];
    float4 bb = ((const float4*)P)[1];
    float v[8] = {a.x, a.y, a.z, a.w, bb.x, bb.y, bb.z, bb.w};

    const float* M = evals + (size_t)e * 64;  // uniform -> scalar loads
    float mm[64];
#pragma unroll
    for (int z = 0; z < 16; ++z) {
      float4 q = ((const float4*)M)[z];
      mm[z * 4 + 0] = q.x; mm[z * 4 + 1] = q.y;
      mm[z * 4 + 2] = q.z; mm[z * 4 + 3] = q.w;
    }

#pragma unroll
    for (int c = 0; c < 8; ++c)
#pragma unroll
      for (int tt = 0; tt < 8; ++tt)
        acc[tt] = fmaf(v[c], mm[c * 8 + tt], acc[tt]);
  }

  float* dst = WT + ((size_t)k * N + i) * 8;
  *(float4*)(dst + 0) = make_float4(acc[0] * 0.125f, acc[1] * 0.125f,
                                    acc[2] * 0.125f, acc[3] * 0.125f);
  *(float4*)(dst + 4) = make_float4(acc[4] * 0.125f, acc[5] * 0.125f,
                                    acc[6] * 0.125f, acc[7] * 0.125f);
}

// ---------------------------------------------------------------------------
// Per-node precompute for out_mlp layer 0:
//   preK[n][o] = sum_c w0[o][16+c] * feat[n][c]           (feat_j role, col k)
//   preI[n][o] = b0[o] + sum_c w0[o][24+c] * feat[n][c]   (feat_i role, row i)
// ---------------------------------------------------------------------------
__global__ __launch_bounds__(256) void node_pre(
    const float* __restrict__ feat, const float* __restrict__ w0,
    const float* __restrict__ b0, float* __restrict__ preK,
    float* __restrict__ preI) {
  const int n = blockIdx.x * 256 + threadIdx.x;
  if (n >= N) return;
  float f[8];
  float4 f0 = ((const float4*)(feat + (size_t)n * 8))[0];
  float4 f1 = ((const float4*)(feat + (size_t)n * 8))[1];
  f[0] = f0.x; f[1] = f0.y; f[2] = f0.z; f[3] = f0.w;
  f[4] = f1.x; f[5] = f1.y; f[6] = f1.z; f[7] = f1.w;
#pragma unroll
  for (int o = 0; o < 32; ++o) {
    float sK = 0.f, sI = b0[o];
#pragma unroll
    for (int c = 0; c < 8; ++c) {
      sK = fmaf(w0[o * 33 + 16 + c], f[c], sK);
      sI = fmaf(w0[o * 33 + 24 + c], f[c], sI);
    }
    preK[n * 32 + o] = sK;
    preI[n * 32 + o] = sI;
  }
}

// ---------------------------------------------------------------------------
// Output MLP: x = [mtr1[i,k,:], mtr1[k,i,:], feat[k], feat[i], (i==k)]
// layer0 uses precomputed node partials; 16x16 (i,k) tile per block.
// ---------------------------------------------------------------------------
__global__ __launch_bounds__(256) void out_mlp(
    const float* __restrict__ mtr, const float* __restrict__ WT,
    const float* __restrict__ preK, const float* __restrict__ preI,
    const float* __restrict__ w0,
    const float* __restrict__ w1, const float* __restrict__ b1,
    const float* __restrict__ w2, const float* __restrict__ b2,
    const float* __restrict__ w3, const float* __restrict__ b3,
    float* __restrict__ out) {
  __shared__ float sK[16][33], sI[16][33];
  const int il = threadIdx.x & 15;
  const int kl = threadIdx.x >> 4;
  const int i = blockIdx.y * 16 + il;
  const int k = blockIdx.x * 16 + kl;

  // stage the 16 preK rows (by k) and 16 preI rows (by i) for this tile
  {
    const int r = threadIdx.x >> 4;   // 0..15
    const int c2 = (threadIdx.x & 15) * 2;
    const float* gK = preK + ((size_t)blockIdx.x * 16 + r) * 32;
    const float* gI = preI + ((size_t)blockIdx.y * 16 + r) * 32;
    sK[r][c2] = gK[c2]; sK[r][c2 + 1] = gK[c2 + 1];
    sI[r][c2] = gI[c2]; sI[r][c2 + 1] = gI[c2 + 1];
  }
  __syncthreads();

  float x[16];
  {
    const float* p1 = WT + ((size_t)k * N + i) * 8;  // mtr1[i,k,:]
    const float* p2 = WT + ((size_t)i * N + k) * 8;  // mtr1[k,i,:]
    float4 a0 = ((const float4*)p1)[0], a1 = ((const float4*)p1)[1];
    float4 c0 = ((const float4*)p2)[0], c1 = ((const float4*)p2)[1];
    x[0] = a0.x; x[1] = a0.y; x[2] = a0.z; x[3] = a0.w;
    x[4] = a1.x; x[5] = a1.y; x[6] = a1.z; x[7] = a1.w;
    x[8] = c0.x; x[9] = c0.y; x[10] = c0.z; x[11] = c0.w;
    x[12] = c1.x; x[13] = c1.y; x[14] = c1.z; x[15] = c1.w;
  }
  const float eye = (i == k) ? 1.f : 0.f;

  float h[32];
#pragma unroll
  for (int o = 0; o < 32; ++o) {
    float acc = sK[kl][o] + sI[il][o];
    acc = fmaf(eye, w0[o * 33 + 32], acc);
#pragma unroll
    for (int c = 0; c < 16; ++c) acc = fmaf(w0[o * 33 + c], x[c], acc);
    h[o] = fmaxf(acc, 0.f);
  }

#pragma unroll 1
  for (int l = 0; l < 2; ++l) {
    const float* W = l ? w2 : w1;
    const float* B = l ? b2 : b1;
    float g[32];
#pragma unroll
    for (int o = 0; o < 32; ++o) {
      float acc = B[o];
#pragma unroll
      for (int c = 0; c < 32; ++c) acc = fmaf(W[o * 32 + c], h[c], acc);
      g[o] = fmaxf(acc, 0.f);
    }
#pragma unroll
    for (int o = 0; o < 32; ++o) h[o] = g[o];
  }

  const size_t idx = ((size_t)i * N + k) * 8;
  float r[8];
#pragma unroll
  for (int t = 0; t < 8; ++t) {
    float acc = b3[t];
#pragma unroll
    for (int c = 0; c < 32; ++c) acc = fmaf(w3[t * 32 + c], h[c], acc);
    r[t] = acc;
  }
  *(float4*)(out + idx + 0) = make_float4(mtr[idx + 0] + r[0], mtr[idx + 1] + r[1],
                                          mtr[idx + 2] + r[2], mtr[idx + 3] + r[3]);
  *(float4*)(out + idx + 4) = make_float4(mtr[idx + 4] + r[4], mtr[idx + 5] + r[5],
                                          mtr[idx + 6] + r[6], mtr[idx + 7] + r[7]);
}

// ---------------------------------------------------------------------------
extern "C" void kernel_launch(void* const* d_in, const int* in_sizes, int n_in,
                              void* d_out, int out_size, void* d_ws,
                              size_t ws_size, hipStream_t stream) {
  const float* mtr  = (const float*)d_in[0];
  const float* feat = (const float*)d_in[1];
  const int*   ei   = (const int*)d_in[2];
  const float* ea   = (const float*)d_in[3];
  const float* ew0 = (const float*)d_in[4];
  const float* eb0 = (const float*)d_in[5];
  const float* ew1 = (const float*)d_in[6];
  const float* eb1 = (const float*)d_in[7];
  const float* ew2 = (const float*)d_in[8];
  const float* eb2 = (const float*)d_in[9];
  const float* ew3 = (const float*)d_in[10];
  const float* eb3 = (const float*)d_in[11];
  const float* ow0 = (const float*)d_in[12];
  const float* ob0 = (const float*)d_in[13];
  const float* ow1 = (const float*)d_in[14];
  const float* ob1 = (const float*)d_in[15];
  const float* ow2 = (const float*)d_in[16];
  const float* ob2 = (const float*)d_in[17];
  const float* ow3 = (const float*)d_in[18];
  const float* ob3 = (const float*)d_in[19];
  float* out = (float*)d_out;

  char* ws = (char*)d_ws;
  float* evals = (float*)ws; ws += (size_t)E * 64 * 4;       // 6.29 MB
  float* mtrT  = (float*)ws; ws += (size_t)N * N * 8 * 4;    // 18.87 MB
  float* WT    = (float*)ws; ws += (size_t)N * N * 8 * 4;    // 18.87 MB
  int* winner  = (int*)ws;   ws += (size_t)N * N * 4;        // 2.36 MB
  int* deg     = (int*)ws;   ws += 1024 * 4;
  int* offs    = (int*)ws;   ws += 1024 * 4;
  int* curs    = (int*)ws;   ws += 1024 * 4;
  int2* ejlist = (int2*)ws;  ws += (size_t)E * 8;            // 196 KB
  float* preK  = (float*)ws; ws += (size_t)N * 32 * 4;       // 98 KB
  float* preI  = (float*)ws; ws += (size_t)N * 32 * 4;       // 98 KB

  hipMemsetAsync(winner, 0xFF, (size_t)N * N * 4, stream);  // -1
  hipMemsetAsync(deg, 0, 1024 * 4, stream);
  hipMemsetAsync(curs, 0, 1024 * 4, stream);

  transpose_mtr<<<dim3(48, 48), 256, 0, stream>>>(mtr, mtrT);
  node_pre<<<3, 256, 0, stream>>>(feat, ow0, ob0, preK, preI);
  edge_mlp<<<E / 256, 256, 0, stream>>>(feat, ei, ea, ew0, eb0, ew1, eb1, ew2,
                                        eb2, ew3, eb3, evals, winner, deg);
  scan_offs<<<1, N, 0, stream>>>(deg, offs);
  scatter_edges<<<E / 256, 256, 0, stream>>>(ei, winner, offs, curs, ejlist);
  contract2<<<2304, 256, 0, stream>>>(mtrT, evals, ejlist, offs, curs, WT);
  out_mlp<<<dim3(48, 48), 256, 0, stream>>>(mtr, WT, preK, preI, ow0, ow1, ob1,
                                            ow2, ob2, ow3, ob3, out);
}